// Round 1
// baseline (447.495 us; speedup 1.0000x reference)
//
#include <hip/hip_runtime.h>
#include <stdint.h>

#define B_N   4096
#define D_DIM 1024
#define INF_F 3.4e38f

// ws layout (bytes):
//   [0]      u64   minpack[4096]   (pack: float-bits(min d) << 32 | j) -> 32768
//   [32768]  u32   maxbits[4096]   (float-bits(max d))                 -> 16384
//   [49152]  f32   norms[4096]                                         -> 16384
//   [65536]  i32   meta[2]  { s_star, n_refs }
//   [65552]  f32   statef[3] { min_d, max_d, R }
//   [65600]  i32   ref_idx[4096]                                       -> 16384
// total ~82 KB

__global__ void k_init(unsigned long long* __restrict__ minpack,
                       unsigned int* __restrict__ maxbits) {
    int i = blockIdx.x * blockDim.x + threadIdx.x;
    if (i < B_N) { minpack[i] = 0xFFFFFFFFFFFFFFFFull; maxbits[i] = 0u; }
}

__global__ void k_norms(const float* __restrict__ x, float* __restrict__ norms) {
    int row  = blockIdx.x * 4 + (threadIdx.x >> 6);
    int lane = threadIdx.x & 63;
    const float* xr = x + (size_t)row * D_DIM;
    float s = 0.f;
    #pragma unroll
    for (int k = 0; k < D_DIM / 64; k++) {
        float v = xr[lane + k * 64];
        s = fmaf(v, v, s);
    }
    #pragma unroll
    for (int off = 32; off; off >>= 1) s += __shfl_down(s, off);
    if (lane == 0) norms[row] = s;
}

// Triangular tiled fp32 "Gram" pass with fused per-row min/argmin/max reduction.
#define BT 128
#define BK 16
__global__ __launch_bounds__(256)
void k_pass1(const float* __restrict__ x, const float* __restrict__ norms,
             unsigned long long* __restrict__ minpack,
             unsigned int* __restrict__ maxbits) {
    int ti = blockIdx.y, tj = blockIdx.x;
    if (tj > ti) return;                       // lower triangle (incl. diagonal)
    __shared__ float As[BK][BT + 4];
    __shared__ float Bs[BK][BT + 4];
    __shared__ unsigned long long redMin[BT][17];
    __shared__ float redMax[BT][17];

    const int i0 = ti * BT, j0 = tj * BT;
    const int t  = threadIdx.x;                // 0..255
    const int tx = t & 15, ty = t >> 4;

    float acc[8][8];
    #pragma unroll
    for (int m = 0; m < 8; m++)
        #pragma unroll
        for (int n = 0; n < 8; n++) acc[m][n] = 0.f;

    for (int k0 = 0; k0 < D_DIM; k0 += BK) {
        #pragma unroll
        for (int l = 0; l < 2; l++) {
            int lin = t + l * 256;             // 0..511
            int r   = lin >> 2;                // 0..127
            int kq  = (lin & 3) * 4;           // 0,4,8,12
            float4 av = *(const float4*)(x + (size_t)(i0 + r) * D_DIM + k0 + kq);
            As[kq + 0][r] = av.x; As[kq + 1][r] = av.y;
            As[kq + 2][r] = av.z; As[kq + 3][r] = av.w;
            float4 bv = *(const float4*)(x + (size_t)(j0 + r) * D_DIM + k0 + kq);
            Bs[kq + 0][r] = bv.x; Bs[kq + 1][r] = bv.y;
            Bs[kq + 2][r] = bv.z; Bs[kq + 3][r] = bv.w;
        }
        __syncthreads();
        #pragma unroll
        for (int k = 0; k < BK; k++) {
            float a[8], b[8];
            #pragma unroll
            for (int m = 0; m < 8; m++) a[m] = As[k][ty * 8 + m];
            #pragma unroll
            for (int n = 0; n < 8; n++) b[n] = Bs[k][tx * 8 + n];
            #pragma unroll
            for (int m = 0; m < 8; m++)
                #pragma unroll
                for (int n = 0; n < 8; n++)
                    acc[m][n] = fmaf(a[m], b[n], acc[m][n]);
        }
        __syncthreads();
    }

    float ni[8], nj[8];
    #pragma unroll
    for (int m = 0; m < 8; m++) ni[m] = norms[i0 + ty * 8 + m];
    #pragma unroll
    for (int n = 0; n < 8; n++) nj[n] = norms[j0 + tx * 8 + n];
    const bool diag = (ti == tj);

    #pragma unroll
    for (int m = 0; m < 8; m++) {
        int i_loc = ty * 8 + m;
        unsigned long long mp = 0xFFFFFFFFFFFFFFFFull;
        float mx = -INF_F;
        #pragma unroll
        for (int n = 0; n < 8; n++) {
            int j_loc = tx * 8 + n;
            if (diag && j_loc >= i_loc) continue;   // strictly j < i
            float d2 = fmaxf(ni[m] + nj[n] - 2.f * acc[m][n], 0.f);
            float d  = sqrtf(d2);
            unsigned long long p =
                ((unsigned long long)__float_as_uint(d) << 32) |
                (unsigned)(j0 + j_loc);
            if (p < mp) mp = p;                     // ties -> lowest j (first-occurrence argmin)
            mx = fmaxf(mx, d);
        }
        redMin[i_loc][tx] = mp;
        redMax[i_loc][tx] = mx;
    }
    __syncthreads();
    if (t < BT) {
        unsigned long long mp = redMin[t][0];
        float mx = redMax[t][0];
        #pragma unroll
        for (int c = 1; c < 16; c++) {
            unsigned long long p = redMin[t][c];
            if (p < mp) mp = p;
            mx = fmaxf(mx, redMax[t][c]);
        }
        if (mp != 0xFFFFFFFFFFFFFFFFull) {
            atomicMin(&minpack[i0 + t], mp);
            atomicMax(&maxbits[i0 + t], __float_as_uint(mx));
        }
    }
}

// Verify the all-insert assumption via prefix min/max recurrence; find first
// violating step s_star (B_N if none). Resolves step s_star itself and stores
// the exact state for the fallback.
__global__ __launch_bounds__(1024)
void k_scan(const unsigned long long* __restrict__ minpack,
            const unsigned int* __restrict__ maxbits,
            const int* __restrict__ labels,
            float* __restrict__ out,
            int* __restrict__ meta, float* __restrict__ statef) {
    const int t = threadIdx.x;
    float m[4], M[4];
    #pragma unroll
    for (int q = 0; q < 4; q++) {
        int i = t * 4 + q;
        unsigned long long p = minpack[i];
        float dmin = (p == 0xFFFFFFFFFFFFFFFFull)
                       ? INF_F : __uint_as_float((unsigned)(p >> 32));
        m[q] = (i == 0) ? INF_F : dmin;          // identity for prefix-min
        M[q] = (i == 0) ? -INF_F : __uint_as_float(maxbits[i]);
    }
    float pmin[4], pmax[4];
    pmin[0] = m[0]; pmax[0] = M[0];
    #pragma unroll
    for (int q = 1; q < 4; q++) {
        pmin[q] = fminf(pmin[q - 1], m[q]);
        pmax[q] = fmaxf(pmax[q - 1], M[q]);
    }
    __shared__ float smin[1024], smax[1024];
    smin[t] = pmin[3]; smax[t] = pmax[3];
    __syncthreads();
    for (int off = 1; off < 1024; off <<= 1) {
        float a = (t >= off) ? smin[t - off] : INF_F;
        float b = (t >= off) ? smax[t - off] : -INF_F;
        __syncthreads();
        smin[t] = fminf(smin[t], a);
        smax[t] = fmaxf(smax[t], b);
        __syncthreads();
    }
    float exMin = (t > 0) ? smin[t - 1] : INF_F;    // exclusive thread prefix
    float exMax = (t > 0) ? smax[t - 1] : -INF_F;

    int viol = B_N;
    #pragma unroll
    for (int q = 0; q < 4; q++) {
        int i = t * 4 + q;
        if (i >= 1) {
            float pm = (q == 0) ? exMin : fminf(exMin, pmin[q - 1]);
            float pM = (q == 0) ? exMax : fmaxf(exMax, pmax[q - 1]);
            float R  = (i == 1) ? 1.0f : (pm + pM) / 3.0f;
            if (!(m[q] > R) && i < viol) viol = i;
        }
    }
    __shared__ int sv[1024];
    sv[t] = viol;
    __syncthreads();
    for (int off = 512; off; off >>= 1) {
        if (t < off) sv[t] = min(sv[t], sv[t + off]);
        __syncthreads();
    }
    int s_star = sv[0];
    if (t == 0) meta[0] = s_star;
    if (s_star < B_N && t == (s_star >> 2)) {
        int q = s_star & 3;
        float pm = (q == 0) ? exMin : fminf(exMin, pmin[q - 1]);
        float pM = (q == 0) ? exMax : fmaxf(exMax, pmax[q - 1]);
        float md = fminf(pm, m[q]);              // state AFTER step s_star
        float Md = fmaxf(pM, M[q]);              // (R updates even on non-insert)
        statef[0] = md; statef[1] = Md; statef[2] = (md + Md) / 3.0f;
        meta[1] = s_star;                        // n_refs = s_star (s_star not inserted)
        unsigned long long p = minpack[s_star];  // pred for the non-insert step itself
        int j = (int)(unsigned)(p & 0xFFFFFFFFu);
        out[s_star] = (float)labels[j];
    }
}

__global__ void k_preds(const int* __restrict__ labels,
                        const int* __restrict__ meta, float* __restrict__ out) {
    int i = blockIdx.x * blockDim.x + threadIdx.x;
    if (i < B_N && i < meta[0]) out[i] = (float)labels[i];  // inserted step -> self label
}

// Correct generic sequential continuation from step s_star+1. Early-exits when
// the speculative pass verified (expected for this data) — cost then ~0.
__global__ __launch_bounds__(256)
void k_fallback(const float* __restrict__ x, const float* __restrict__ norms,
                const int* __restrict__ labels, const int* __restrict__ meta,
                const float* __restrict__ statef, int* __restrict__ ref_idx,
                float* __restrict__ out) {
    int s_star = meta[0];
    if (s_star >= B_N) return;
    const int t = threadIdx.x;
    __shared__ float s_state[3];
    __shared__ int s_n;
    __shared__ unsigned long long redp[256];
    __shared__ float redm[256];
    if (t == 0) {
        s_state[0] = statef[0]; s_state[1] = statef[1]; s_state[2] = statef[2];
        s_n = meta[1];
    }
    for (int s = t; s < s_star; s += 256) ref_idx[s] = s;
    __syncthreads();

    for (int i = s_star + 1; i < B_N; i++) {
        int n = s_n;
        const float* xi = x + (size_t)i * D_DIM;
        float ni = norms[i];
        unsigned long long mp = 0xFFFFFFFFFFFFFFFFull;
        float mx = -INF_F;
        for (int slot = t; slot < n; slot += 256) {
            int j = ref_idx[slot];
            const float* xj = x + (size_t)j * D_DIM;
            float dot = 0.f;
            for (int k = 0; k < D_DIM; k++) dot = fmaf(xi[k], xj[k], dot);
            float d = sqrtf(fmaxf(ni + norms[j] - 2.f * dot, 0.f));
            unsigned long long p =
                ((unsigned long long)__float_as_uint(d) << 32) | (unsigned)slot;
            if (p < mp) mp = p;
            mx = fmaxf(mx, d);
        }
        redp[t] = mp; redm[t] = mx;
        __syncthreads();
        for (int off = 128; off; off >>= 1) {
            if (t < off) {
                if (redp[t + off] < redp[t]) redp[t] = redp[t + off];
                redm[t] = fmaxf(redm[t], redm[t + off]);
            }
            __syncthreads();
        }
        if (t == 0) {
            unsigned long long p = redp[0];
            float min_act = __uint_as_float((unsigned)(p >> 32));
            int minslot   = (int)(unsigned)(p & 0xFFFFFFFFu);
            float max_act = redm[0];
            bool insert = (min_act > s_state[2]);
            int pred;
            if (insert) {
                ref_idx[n] = i;
                s_n = n + 1;
                // new self-ref has d == 0 exactly; an earlier ref ties only at d==0
                pred = (min_act <= 0.0f) ? labels[ref_idx[minslot]] : labels[i];
            } else {
                pred = labels[ref_idx[minslot]];
            }
            float md = fminf(s_state[0], min_act);
            float Md = fmaxf(s_state[1], max_act);
            s_state[0] = md; s_state[1] = Md; s_state[2] = (md + Md) / 3.0f;
            out[i] = (float)pred;
        }
        __syncthreads();
    }
}

extern "C" void kernel_launch(void* const* d_in, const int* in_sizes, int n_in,
                              void* d_out, int out_size, void* d_ws, size_t ws_size,
                              hipStream_t stream) {
    const float* x      = (const float*)d_in[0];
    const int*   labels = (const int*)d_in[1];
    float*       out    = (float*)d_out;
    char* ws = (char*)d_ws;
    unsigned long long* minpack = (unsigned long long*)ws;
    unsigned int*       maxbits = (unsigned int*)(ws + 32768);
    float*              norms   = (float*)(ws + 49152);
    int*                meta    = (int*)(ws + 65536);
    float*              statef  = (float*)(ws + 65552);
    int*                ref_idx = (int*)(ws + 65600);

    k_init<<<B_N / 256, 256, 0, stream>>>(minpack, maxbits);
    k_norms<<<B_N / 4, 256, 0, stream>>>(x, norms);
    dim3 grid(B_N / BT, B_N / BT);
    k_pass1<<<grid, 256, 0, stream>>>(x, norms, minpack, maxbits);
    k_scan<<<1, 1024, 0, stream>>>(minpack, maxbits, labels, out, meta, statef);
    k_preds<<<B_N / 256, 256, 0, stream>>>(labels, meta, out);
    k_fallback<<<1, 256, 0, stream>>>(x, norms, labels, meta, statef, ref_idx, out);
}

// Round 2
// 132.738 us; speedup vs baseline: 3.3713x; 3.3713x over previous
//
#include <hip/hip_runtime.h>
#include <stdint.h>

#define B_N   4096
#define D_DIM 1024
#define INF_F 3.4e38f

typedef __bf16 bf16x8 __attribute__((ext_vector_type(8)));
typedef float  floatx4 __attribute__((ext_vector_type(4)));

// ws layout (bytes):
//   [0]      u64   minpack[4096]   (pack: float-bits(min d) << 32 | j) -> 32768
//   [32768]  u32   maxbits[4096]   (float-bits(max d))                 -> 16384
//   [49152]  f32   norms[4096]                                         -> 16384
//   [65536]  i32   meta[2]  { s_star, n_refs }
//   [65552]  f32   statef[3] { min_d, max_d, R }
//   [65600]  i32   ref_idx[4096]                                       -> 16384
//   [131072] bf16  xbf[4096*1024]                                      -> 8 MB
#define XBF_OFF 131072

__global__ void k_init(unsigned long long* __restrict__ minpack,
                       unsigned int* __restrict__ maxbits) {
    int i = blockIdx.x * blockDim.x + threadIdx.x;
    if (i < B_N) { minpack[i] = 0xFFFFFFFFFFFFFFFFull; maxbits[i] = 0u; }
}

__device__ inline unsigned short f2bf_rne(float f) {
    unsigned u = __float_as_uint(f);
    unsigned r = (u + 0x7FFFu + ((u >> 16) & 1u)) >> 16;
    return (unsigned short)r;
}

__global__ void k_cast(const float* __restrict__ x, unsigned short* __restrict__ xbf) {
    int i = blockIdx.x * 256 + threadIdx.x;       // 1M threads, 4 floats each
    float4 v = ((const float4*)x)[i];
    ushort4 o;
    o.x = f2bf_rne(v.x); o.y = f2bf_rne(v.y);
    o.z = f2bf_rne(v.z); o.w = f2bf_rne(v.w);
    ((ushort4*)xbf)[i] = o;
}

__global__ void k_norms(const float* __restrict__ x, float* __restrict__ norms) {
    int row  = blockIdx.x * 4 + (threadIdx.x >> 6);
    int lane = threadIdx.x & 63;
    const float* xr = x + (size_t)row * D_DIM;
    float s = 0.f;
    #pragma unroll
    for (int k = 0; k < D_DIM / 64; k++) {
        float v = xr[lane + k * 64];
        s = fmaf(v, v, s);
    }
    #pragma unroll
    for (int off = 32; off; off >>= 1) s += __shfl_down(s, off);
    if (lane == 0) norms[row] = s;
}

#define GLDS(g, l)                                                              \
    __builtin_amdgcn_global_load_lds(                                           \
        (__attribute__((address_space(1))) void*)(void*)(g),                    \
        (__attribute__((address_space(3))) void*)(void*)(l), 16, 0, 0)

// MFMA Gram pass over the lower triangle with fused per-row min/argmin/max.
// LDS chunk layout XOR-swizzled: (row, kgroup) at chunk (row*8 + (kgroup^(row&7))).
__global__ __launch_bounds__(256, 2)
void k_pass1_mfma(const unsigned short* __restrict__ xbf,
                  const float* __restrict__ norms,
                  unsigned long long* __restrict__ minpack,
                  unsigned int* __restrict__ maxbits) {
    const int ti = blockIdx.y, tj = blockIdx.x;
    if (tj > ti) return;
    __shared__ unsigned short As[8192];           // 128 rows x 64 bf16
    __shared__ unsigned short Bs[8192];
    __shared__ unsigned long long redMin[128][2];
    __shared__ float redMax[128][2];

    const int t    = threadIdx.x;
    const int w    = t >> 6, lane = t & 63;
    const int wm   = w >> 1, wn = w & 1;          // 64x64 quadrant per wave
    const int q4   = lane >> 4, c15 = lane & 15, l7 = lane & 7;
    const int lr   = lane >> 3;                   // 0..7
    const int kg   = (lane & 7) ^ lr;             // swizzled kgroup for staging
    const int i0   = ti * 128, j0 = tj * 128;

    const unsigned short* gA[4]; const unsigned short* gB[4];
    unsigned short* lA[4]; unsigned short* lB[4];
    #pragma unroll
    for (int q = 0; q < 4; q++) {
        int e   = w * 4 + q;                      // instruction slot 0..15
        int row = e * 8 + lr;                     // tile row this lane fetches
        gA[q] = xbf + (size_t)(i0 + row) * D_DIM + kg * 8;
        gB[q] = xbf + (size_t)(j0 + row) * D_DIM + kg * 8;
        lA[q] = As + e * 512;                     // 1 KB (512 ushort) per instr
        lB[q] = Bs + e * 512;
    }

    // fragment LDS byte offsets (row*128 + swizzled kgroup*16)
    int aoff[4][2], boff[4][2];
    #pragma unroll
    for (int st = 0; st < 4; st++) {
        #pragma unroll
        for (int kk = 0; kk < 2; kk++) {
            int g = ((kk * 4 + q4) ^ l7) << 4;
            aoff[st][kk] = (wm * 64 + st * 16 + c15) * 128 + g;
            boff[st][kk] = (wn * 64 + st * 16 + c15) * 128 + g;
        }
    }

    floatx4 acc[4][4];
    #pragma unroll
    for (int m = 0; m < 4; m++)
        #pragma unroll
        for (int n = 0; n < 4; n++)
            acc[m][n] = (floatx4){0.f, 0.f, 0.f, 0.f};

    for (int it = 0; it < 16; it++) {             // K = 1024, BK = 64
        __syncthreads();
        #pragma unroll
        for (int q = 0; q < 4; q++) {
            GLDS(gA[q], lA[q]);
            GLDS(gB[q], lB[q]);
            gA[q] += 64; gB[q] += 64;
        }
        __syncthreads();
        #pragma unroll
        for (int kk = 0; kk < 2; kk++) {
            bf16x8 af[4], bfr[4];
            #pragma unroll
            for (int st = 0; st < 4; st++) {
                af[st]  = *(const bf16x8*)((const char*)As + aoff[st][kk]);
                bfr[st] = *(const bf16x8*)((const char*)Bs + boff[st][kk]);
            }
            #pragma unroll
            for (int m = 0; m < 4; m++)
                #pragma unroll
                for (int n = 0; n < 4; n++)
                    acc[m][n] = __builtin_amdgcn_mfma_f32_16x16x32_bf16(
                        af[m], bfr[n], acc[m][n], 0, 0, 0);
        }
    }

    // epilogue: d = sqrt(ni + nj - 2*dot), strictly j < i; min-pack + max per row
    float nj[4];
    #pragma unroll
    for (int st = 0; st < 4; st++) nj[st] = norms[j0 + wn * 64 + st * 16 + c15];

    #pragma unroll
    for (int st_m = 0; st_m < 4; st_m++) {
        #pragma unroll
        for (int r = 0; r < 4; r++) {
            int i_loc = wm * 64 + st_m * 16 + q4 * 4 + r;
            int gi    = i0 + i_loc;
            float ni  = norms[gi];
            unsigned long long mp = 0xFFFFFFFFFFFFFFFFull;
            float mx = -INF_F;
            #pragma unroll
            for (int st_n = 0; st_n < 4; st_n++) {
                int gj = j0 + wn * 64 + st_n * 16 + c15;
                if (gj < gi) {
                    float dot = acc[st_m][st_n][r];
                    float d   = sqrtf(fmaxf(ni + nj[st_n] - 2.f * dot, 0.f));
                    unsigned long long p =
                        ((unsigned long long)__float_as_uint(d) << 32) | (unsigned)gj;
                    if (p < mp) mp = p;
                    mx = fmaxf(mx, d);
                }
            }
            // butterfly over the 16 lanes sharing this row (low 4 lane bits)
            #pragma unroll
            for (int off = 1; off < 16; off <<= 1) {
                unsigned long long op = __shfl_xor(mp, off, 64);
                if (op < mp) mp = op;
                float om = __shfl_xor(mx, off, 64);
                mx = fmaxf(mx, om);
            }
            if (c15 == 0) { redMin[i_loc][wn] = mp; redMax[i_loc][wn] = mx; }
        }
    }
    __syncthreads();
    if (t < 128) {
        unsigned long long mp = redMin[t][0];
        if (redMin[t][1] < mp) mp = redMin[t][1];
        float mx = fmaxf(redMax[t][0], redMax[t][1]);
        if (mp != 0xFFFFFFFFFFFFFFFFull) {
            atomicMin(&minpack[i0 + t], mp);
            atomicMax(&maxbits[i0 + t], __float_as_uint(mx));
        }
    }
}

// fp32 exact pass — only used if ws_size can't hold the bf16 copy.
#define BT 128
#define BK 16
__global__ __launch_bounds__(256)
void k_pass1_f32(const float* __restrict__ x, const float* __restrict__ norms,
                 unsigned long long* __restrict__ minpack,
                 unsigned int* __restrict__ maxbits) {
    int ti = blockIdx.y, tj = blockIdx.x;
    if (tj > ti) return;
    __shared__ float As[BK][BT + 4];
    __shared__ float Bs[BK][BT + 4];
    __shared__ unsigned long long redMin[BT][17];
    __shared__ float redMax[BT][17];

    const int i0 = ti * BT, j0 = tj * BT;
    const int t  = threadIdx.x;
    const int tx = t & 15, ty = t >> 4;

    float acc[8][8];
    #pragma unroll
    for (int m = 0; m < 8; m++)
        #pragma unroll
        for (int n = 0; n < 8; n++) acc[m][n] = 0.f;

    for (int k0 = 0; k0 < D_DIM; k0 += BK) {
        #pragma unroll
        for (int l = 0; l < 2; l++) {
            int lin = t + l * 256;
            int r   = lin >> 2;
            int kq  = (lin & 3) * 4;
            float4 av = *(const float4*)(x + (size_t)(i0 + r) * D_DIM + k0 + kq);
            As[kq + 0][r] = av.x; As[kq + 1][r] = av.y;
            As[kq + 2][r] = av.z; As[kq + 3][r] = av.w;
            float4 bv = *(const float4*)(x + (size_t)(j0 + r) * D_DIM + k0 + kq);
            Bs[kq + 0][r] = bv.x; Bs[kq + 1][r] = bv.y;
            Bs[kq + 2][r] = bv.z; Bs[kq + 3][r] = bv.w;
        }
        __syncthreads();
        #pragma unroll
        for (int k = 0; k < BK; k++) {
            float a[8], b[8];
            #pragma unroll
            for (int m = 0; m < 8; m++) a[m] = As[k][ty * 8 + m];
            #pragma unroll
            for (int n = 0; n < 8; n++) b[n] = Bs[k][tx * 8 + n];
            #pragma unroll
            for (int m = 0; m < 8; m++)
                #pragma unroll
                for (int n = 0; n < 8; n++)
                    acc[m][n] = fmaf(a[m], b[n], acc[m][n]);
        }
        __syncthreads();
    }

    float ni[8], njv[8];
    #pragma unroll
    for (int m = 0; m < 8; m++) ni[m] = norms[i0 + ty * 8 + m];
    #pragma unroll
    for (int n = 0; n < 8; n++) njv[n] = norms[j0 + tx * 8 + n];
    const bool diag = (ti == tj);

    #pragma unroll
    for (int m = 0; m < 8; m++) {
        int i_loc = ty * 8 + m;
        unsigned long long mp = 0xFFFFFFFFFFFFFFFFull;
        float mx = -INF_F;
        #pragma unroll
        for (int n = 0; n < 8; n++) {
            int j_loc = tx * 8 + n;
            if (diag && j_loc >= i_loc) continue;
            float d2 = fmaxf(ni[m] + njv[n] - 2.f * acc[m][n], 0.f);
            float d  = sqrtf(d2);
            unsigned long long p =
                ((unsigned long long)__float_as_uint(d) << 32) |
                (unsigned)(j0 + j_loc);
            if (p < mp) mp = p;
            mx = fmaxf(mx, d);
        }
        redMin[i_loc][tx] = mp;
        redMax[i_loc][tx] = mx;
    }
    __syncthreads();
    if (t < BT) {
        unsigned long long mp = redMin[t][0];
        float mx = redMax[t][0];
        #pragma unroll
        for (int c = 1; c < 16; c++) {
            unsigned long long p = redMin[t][c];
            if (p < mp) mp = p;
            mx = fmaxf(mx, redMax[t][c]);
        }
        if (mp != 0xFFFFFFFFFFFFFFFFull) {
            atomicMin(&minpack[i0 + t], mp);
            atomicMax(&maxbits[i0 + t], __float_as_uint(mx));
        }
    }
}

__global__ __launch_bounds__(1024)
void k_scan(const unsigned long long* __restrict__ minpack,
            const unsigned int* __restrict__ maxbits,
            const int* __restrict__ labels,
            float* __restrict__ out,
            int* __restrict__ meta, float* __restrict__ statef) {
    const int t = threadIdx.x;
    float m[4], M[4];
    #pragma unroll
    for (int q = 0; q < 4; q++) {
        int i = t * 4 + q;
        unsigned long long p = minpack[i];
        float dmin = (p == 0xFFFFFFFFFFFFFFFFull)
                       ? INF_F : __uint_as_float((unsigned)(p >> 32));
        m[q] = (i == 0) ? INF_F : dmin;
        M[q] = (i == 0) ? -INF_F : __uint_as_float(maxbits[i]);
    }
    float pmin[4], pmax[4];
    pmin[0] = m[0]; pmax[0] = M[0];
    #pragma unroll
    for (int q = 1; q < 4; q++) {
        pmin[q] = fminf(pmin[q - 1], m[q]);
        pmax[q] = fmaxf(pmax[q - 1], M[q]);
    }
    __shared__ float smin[1024], smax[1024];
    smin[t] = pmin[3]; smax[t] = pmax[3];
    __syncthreads();
    for (int off = 1; off < 1024; off <<= 1) {
        float a = (t >= off) ? smin[t - off] : INF_F;
        float b = (t >= off) ? smax[t - off] : -INF_F;
        __syncthreads();
        smin[t] = fminf(smin[t], a);
        smax[t] = fmaxf(smax[t], b);
        __syncthreads();
    }
    float exMin = (t > 0) ? smin[t - 1] : INF_F;
    float exMax = (t > 0) ? smax[t - 1] : -INF_F;

    int viol = B_N;
    #pragma unroll
    for (int q = 0; q < 4; q++) {
        int i = t * 4 + q;
        if (i >= 1) {
            float pm = (q == 0) ? exMin : fminf(exMin, pmin[q - 1]);
            float pM = (q == 0) ? exMax : fmaxf(exMax, pmax[q - 1]);
            float R  = (i == 1) ? 1.0f : (pm + pM) / 3.0f;
            if (!(m[q] > R) && i < viol) viol = i;
        }
    }
    __shared__ int sv[1024];
    sv[t] = viol;
    __syncthreads();
    for (int off = 512; off; off >>= 1) {
        if (t < off) sv[t] = min(sv[t], sv[t + off]);
        __syncthreads();
    }
    int s_star = sv[0];
    if (t == 0) meta[0] = s_star;
    if (s_star < B_N && t == (s_star >> 2)) {
        int q = s_star & 3;
        float pm = (q == 0) ? exMin : fminf(exMin, pmin[q - 1]);
        float pM = (q == 0) ? exMax : fmaxf(exMax, pmax[q - 1]);
        float md = fminf(pm, m[q]);
        float Md = fmaxf(pM, M[q]);
        statef[0] = md; statef[1] = Md; statef[2] = (md + Md) / 3.0f;
        meta[1] = s_star;
        unsigned long long p = minpack[s_star];
        int j = (int)(unsigned)(p & 0xFFFFFFFFu);
        out[s_star] = (float)labels[j];
    }
}

__global__ void k_preds(const int* __restrict__ labels,
                        const int* __restrict__ meta, float* __restrict__ out) {
    int i = blockIdx.x * blockDim.x + threadIdx.x;
    if (i < B_N && i < meta[0]) out[i] = (float)labels[i];
}

__global__ __launch_bounds__(256)
void k_fallback(const float* __restrict__ x, const float* __restrict__ norms,
                const int* __restrict__ labels, const int* __restrict__ meta,
                const float* __restrict__ statef, int* __restrict__ ref_idx,
                float* __restrict__ out) {
    int s_star = meta[0];
    if (s_star >= B_N) return;
    const int t = threadIdx.x;
    __shared__ float s_state[3];
    __shared__ int s_n;
    __shared__ unsigned long long redp[256];
    __shared__ float redm[256];
    if (t == 0) {
        s_state[0] = statef[0]; s_state[1] = statef[1]; s_state[2] = statef[2];
        s_n = meta[1];
    }
    for (int s = t; s < s_star; s += 256) ref_idx[s] = s;
    __syncthreads();

    for (int i = s_star + 1; i < B_N; i++) {
        int n = s_n;
        const float* xi = x + (size_t)i * D_DIM;
        float ni = norms[i];
        unsigned long long mp = 0xFFFFFFFFFFFFFFFFull;
        float mx = -INF_F;
        for (int slot = t; slot < n; slot += 256) {
            int j = ref_idx[slot];
            const float* xj = x + (size_t)j * D_DIM;
            float dot = 0.f;
            for (int k = 0; k < D_DIM; k++) dot = fmaf(xi[k], xj[k], dot);
            float d = sqrtf(fmaxf(ni + norms[j] - 2.f * dot, 0.f));
            unsigned long long p =
                ((unsigned long long)__float_as_uint(d) << 32) | (unsigned)slot;
            if (p < mp) mp = p;
            mx = fmaxf(mx, d);
        }
        redp[t] = mp; redm[t] = mx;
        __syncthreads();
        for (int off = 128; off; off >>= 1) {
            if (t < off) {
                if (redp[t + off] < redp[t]) redp[t] = redp[t + off];
                redm[t] = fmaxf(redm[t], redm[t + off]);
            }
            __syncthreads();
        }
        if (t == 0) {
            unsigned long long p = redp[0];
            float min_act = __uint_as_float((unsigned)(p >> 32));
            int minslot   = (int)(unsigned)(p & 0xFFFFFFFFu);
            float max_act = redm[0];
            bool insert = (min_act > s_state[2]);
            int pred;
            if (insert) {
                ref_idx[n] = i;
                s_n = n + 1;
                pred = (min_act <= 0.0f) ? labels[ref_idx[minslot]] : labels[i];
            } else {
                pred = labels[ref_idx[minslot]];
            }
            float md = fminf(s_state[0], min_act);
            float Md = fmaxf(s_state[1], max_act);
            s_state[0] = md; s_state[1] = Md; s_state[2] = (md + Md) / 3.0f;
            out[i] = (float)pred;
        }
        __syncthreads();
    }
}

extern "C" void kernel_launch(void* const* d_in, const int* in_sizes, int n_in,
                              void* d_out, int out_size, void* d_ws, size_t ws_size,
                              hipStream_t stream) {
    const float* x      = (const float*)d_in[0];
    const int*   labels = (const int*)d_in[1];
    float*       out    = (float*)d_out;
    char* ws = (char*)d_ws;
    unsigned long long* minpack = (unsigned long long*)ws;
    unsigned int*       maxbits = (unsigned int*)(ws + 32768);
    float*              norms   = (float*)(ws + 49152);
    int*                meta    = (int*)(ws + 65536);
    float*              statef  = (float*)(ws + 65552);
    int*                ref_idx = (int*)(ws + 65600);
    unsigned short*     xbf     = (unsigned short*)(ws + XBF_OFF);

    const bool use_mfma =
        ws_size >= (size_t)XBF_OFF + (size_t)B_N * D_DIM * 2;

    k_init<<<B_N / 256, 256, 0, stream>>>(minpack, maxbits);
    k_norms<<<B_N / 4, 256, 0, stream>>>(x, norms);
    dim3 grid(B_N / 128, B_N / 128);
    if (use_mfma) {
        k_cast<<<B_N * D_DIM / 4 / 256, 256, 0, stream>>>(x, xbf);
        k_pass1_mfma<<<grid, 256, 0, stream>>>(xbf, norms, minpack, maxbits);
    } else {
        k_pass1_f32<<<grid, 256, 0, stream>>>(x, norms, minpack, maxbits);
    }
    k_scan<<<1, 1024, 0, stream>>>(minpack, maxbits, labels, out, meta, statef);
    k_preds<<<B_N / 256, 256, 0, stream>>>(labels, meta, out);
    k_fallback<<<1, 256, 0, stream>>>(x, norms, labels, meta, statef, ref_idx, out);
}

// Round 3
// 104.273 us; speedup vs baseline: 4.2916x; 1.2730x over previous
//
#include <hip/hip_runtime.h>
#include <stdint.h>

#define B_N   4096
#define D_DIM 1024
#define INF_F 3.4e38f

typedef __bf16 bf16x8 __attribute__((ext_vector_type(8)));
typedef float  floatx4 __attribute__((ext_vector_type(4)));

// ws layout (bytes):
//   [0]      u64   minpack[4096]   (pack: float-bits(min d) << 32 | j) -> 32768
//   [32768]  u32   maxbits[4096]   (float-bits(max d))                 -> 16384
//   [49152]  f32   norms[4096]                                         -> 16384
//   [65600]  i32   ref_idx[4096]                                       -> 16384
//   [131072] bf16  xbf[4096*1024]                                      -> 8 MB
#define XBF_OFF 131072

__device__ inline unsigned short f2bf_rne(float f) {
    unsigned u = __float_as_uint(f);
    unsigned r = (u + 0x7FFFu + ((u >> 16) & 1u)) >> 16;
    return (unsigned short)r;
}

// One block per row: cast to bf16, row sum-of-squares, and init minpack/maxbits.
__global__ __launch_bounds__(256)
void k_prep(const float* __restrict__ x, unsigned short* __restrict__ xbf,
            float* __restrict__ norms,
            unsigned long long* __restrict__ minpack,
            unsigned int* __restrict__ maxbits) {
    const int row = blockIdx.x;
    const int t   = threadIdx.x;
    float4 v = ((const float4*)x)[row * 256 + t];
    ushort4 o;
    o.x = f2bf_rne(v.x); o.y = f2bf_rne(v.y);
    o.z = f2bf_rne(v.z); o.w = f2bf_rne(v.w);
    ((ushort4*)xbf)[row * 256 + t] = o;
    float s = v.x * v.x + v.y * v.y + v.z * v.z + v.w * v.w;
    #pragma unroll
    for (int off = 32; off; off >>= 1) s += __shfl_down(s, off);
    __shared__ float ws4[4];
    if ((t & 63) == 0) ws4[t >> 6] = s;
    __syncthreads();
    if (t == 0) {
        norms[row]   = ws4[0] + ws4[1] + ws4[2] + ws4[3];
        minpack[row] = 0xFFFFFFFFFFFFFFFFull;
        maxbits[row] = 0u;
    }
}

#define GLDS(g, l)                                                              \
    __builtin_amdgcn_global_load_lds(                                           \
        (__attribute__((address_space(1))) void*)(void*)(g),                    \
        (__attribute__((address_space(3))) void*)(void*)(l), 16, 0, 0)

// MFMA Gram pass over the lower triangle with fused per-row min/argmin/max.
// Grid is exactly the 528 lower-triangle tiles (linear triangular decode).
__global__ __launch_bounds__(256, 3)
void k_pass1_mfma(const unsigned short* __restrict__ xbf,
                  const float* __restrict__ norms,
                  unsigned long long* __restrict__ minpack,
                  unsigned int* __restrict__ maxbits) {
    // decode linear block id -> (ti, tj), tj <= ti
    int bid = blockIdx.x;
    int ti  = (int)((sqrtf(8.f * bid + 1.f) - 1.f) * 0.5f);
    while ((ti + 1) * (ti + 2) / 2 <= bid) ti++;
    while (ti * (ti + 1) / 2 > bid) ti--;
    int tj  = bid - ti * (ti + 1) / 2;

    __shared__ unsigned short As[8192];           // 128 rows x 64 bf16 (chunk-swizzled)
    __shared__ unsigned short Bs[8192];
    __shared__ unsigned long long redMin[128][2];
    __shared__ float redMax[128][2];

    const int t    = threadIdx.x;
    const int w    = t >> 6, lane = t & 63;
    const int wm   = w >> 1, wn = w & 1;          // 64x64 quadrant per wave
    const int q4   = lane >> 4, c15 = lane & 15, l7 = lane & 7;
    const int lr   = lane >> 3;                   // 0..7
    const int kg   = (lane & 7) ^ lr;             // swizzled kgroup for staging
    const int i0   = ti * 128, j0 = tj * 128;

    const unsigned short* gA[4]; const unsigned short* gB[4];
    unsigned short* lA[4]; unsigned short* lB[4];
    #pragma unroll
    for (int q = 0; q < 4; q++) {
        int e   = w * 4 + q;                      // instruction slot 0..15
        int row = e * 8 + lr;                     // tile row this lane fetches
        gA[q] = xbf + (size_t)(i0 + row) * D_DIM + kg * 8;
        gB[q] = xbf + (size_t)(j0 + row) * D_DIM + kg * 8;
        lA[q] = As + e * 512;                     // 1 KB (512 ushort) per instr
        lB[q] = Bs + e * 512;
    }

    int aoff[4][2], boff[4][2];
    #pragma unroll
    for (int st = 0; st < 4; st++) {
        #pragma unroll
        for (int kk = 0; kk < 2; kk++) {
            int g = ((kk * 4 + q4) ^ l7) << 4;
            aoff[st][kk] = (wm * 64 + st * 16 + c15) * 128 + g;
            boff[st][kk] = (wn * 64 + st * 16 + c15) * 128 + g;
        }
    }

    floatx4 acc[4][4];
    #pragma unroll
    for (int m = 0; m < 4; m++)
        #pragma unroll
        for (int n = 0; n < 4; n++)
            acc[m][n] = (floatx4){0.f, 0.f, 0.f, 0.f};

    for (int it = 0; it < 16; it++) {             // K = 1024, BK = 64
        __syncthreads();
        #pragma unroll
        for (int q = 0; q < 4; q++) {
            GLDS(gA[q], lA[q]);
            GLDS(gB[q], lB[q]);
            gA[q] += 64; gB[q] += 64;
        }
        __syncthreads();
        #pragma unroll
        for (int kk = 0; kk < 2; kk++) {
            bf16x8 af[4], bfr[4];
            #pragma unroll
            for (int st = 0; st < 4; st++) {
                af[st]  = *(const bf16x8*)((const char*)As + aoff[st][kk]);
                bfr[st] = *(const bf16x8*)((const char*)Bs + boff[st][kk]);
            }
            #pragma unroll
            for (int m = 0; m < 4; m++)
                #pragma unroll
                for (int n = 0; n < 4; n++)
                    acc[m][n] = __builtin_amdgcn_mfma_f32_16x16x32_bf16(
                        af[m], bfr[n], acc[m][n], 0, 0, 0);
        }
    }

    float nj[4];
    #pragma unroll
    for (int st = 0; st < 4; st++) nj[st] = norms[j0 + wn * 64 + st * 16 + c15];

    #pragma unroll
    for (int st_m = 0; st_m < 4; st_m++) {
        #pragma unroll
        for (int r = 0; r < 4; r++) {
            int i_loc = wm * 64 + st_m * 16 + q4 * 4 + r;
            int gi    = i0 + i_loc;
            float ni  = norms[gi];
            unsigned long long mp = 0xFFFFFFFFFFFFFFFFull;
            float mx = -INF_F;
            #pragma unroll
            for (int st_n = 0; st_n < 4; st_n++) {
                int gj = j0 + wn * 64 + st_n * 16 + c15;
                if (gj < gi) {
                    float dot = acc[st_m][st_n][r];
                    float d   = sqrtf(fmaxf(ni + nj[st_n] - 2.f * dot, 0.f));
                    unsigned long long p =
                        ((unsigned long long)__float_as_uint(d) << 32) | (unsigned)gj;
                    if (p < mp) mp = p;
                    mx = fmaxf(mx, d);
                }
            }
            #pragma unroll
            for (int off = 1; off < 16; off <<= 1) {
                unsigned long long op = __shfl_xor(mp, off, 64);
                if (op < mp) mp = op;
                float om = __shfl_xor(mx, off, 64);
                mx = fmaxf(mx, om);
            }
            if (c15 == 0) { redMin[i_loc][wn] = mp; redMax[i_loc][wn] = mx; }
        }
    }
    __syncthreads();
    if (t < 128) {
        unsigned long long mp = redMin[t][0];
        if (redMin[t][1] < mp) mp = redMin[t][1];
        float mx = fmaxf(redMax[t][0], redMax[t][1]);
        if (mp != 0xFFFFFFFFFFFFFFFFull) {
            atomicMin(&minpack[i0 + t], mp);
            atomicMax(&maxbits[i0 + t], __float_as_uint(mx));
        }
    }
}

// Fused: verify all-insert assumption (prefix min/max scan), emit fast-path
// predictions, and — only if verification failed at s_star — run the exact
// sequential continuation. Single block, 1024 threads.
__global__ __launch_bounds__(1024)
void k_tail(const unsigned long long* __restrict__ minpack,
            const unsigned int* __restrict__ maxbits,
            const float* __restrict__ x, const float* __restrict__ norms,
            const int* __restrict__ labels, int* __restrict__ ref_idx,
            float* __restrict__ out) {
    const int t = threadIdx.x;
    float m[4], M[4];
    #pragma unroll
    for (int q = 0; q < 4; q++) {
        int i = t * 4 + q;
        unsigned long long p = minpack[i];
        float dmin = (p == 0xFFFFFFFFFFFFFFFFull)
                       ? INF_F : __uint_as_float((unsigned)(p >> 32));
        m[q] = (i == 0) ? INF_F : dmin;
        M[q] = (i == 0) ? -INF_F : __uint_as_float(maxbits[i]);
    }
    float pmin[4], pmax[4];
    pmin[0] = m[0]; pmax[0] = M[0];
    #pragma unroll
    for (int q = 1; q < 4; q++) {
        pmin[q] = fminf(pmin[q - 1], m[q]);
        pmax[q] = fmaxf(pmax[q - 1], M[q]);
    }
    __shared__ float smin[1024], smax[1024];
    smin[t] = pmin[3]; smax[t] = pmax[3];
    __syncthreads();
    for (int off = 1; off < 1024; off <<= 1) {
        float a = (t >= off) ? smin[t - off] : INF_F;
        float b = (t >= off) ? smax[t - off] : -INF_F;
        __syncthreads();
        smin[t] = fminf(smin[t], a);
        smax[t] = fmaxf(smax[t], b);
        __syncthreads();
    }
    float exMin = (t > 0) ? smin[t - 1] : INF_F;
    float exMax = (t > 0) ? smax[t - 1] : -INF_F;

    int viol = B_N;
    #pragma unroll
    for (int q = 0; q < 4; q++) {
        int i = t * 4 + q;
        if (i >= 1) {
            float pm = (q == 0) ? exMin : fminf(exMin, pmin[q - 1]);
            float pM = (q == 0) ? exMax : fmaxf(exMax, pmax[q - 1]);
            float R  = (i == 1) ? 1.0f : (pm + pM) / 3.0f;
            if (!(m[q] > R) && i < viol) viol = i;
        }
    }
    __shared__ int sv[1024];
    sv[t] = viol;
    __syncthreads();
    for (int off = 512; off; off >>= 1) {
        if (t < off) sv[t] = min(sv[t], sv[t + off]);
        __syncthreads();
    }
    const int s_star = sv[0];

    // fast-path outputs: every verified step inserted -> pred = own label
    for (int i = t; i < s_star; i += 1024) out[i] = (float)labels[i];

    __shared__ float s_state[3];
    __shared__ int s_n;
    if (s_star < B_N && t == (s_star >> 2)) {
        int q = s_star & 3;
        float pm = (q == 0) ? exMin : fminf(exMin, pmin[q - 1]);
        float pM = (q == 0) ? exMax : fmaxf(exMax, pmax[q - 1]);
        float md = fminf(pm, m[q]);              // state AFTER step s_star
        float Md = fmaxf(pM, M[q]);              // (R updates even on non-insert)
        s_state[0] = md; s_state[1] = Md; s_state[2] = (md + Md) / 3.0f;
        s_n = s_star;                            // refs are exactly 0..s_star-1
        unsigned long long p = minpack[s_star];  // pred for the non-insert step
        int j = (int)(unsigned)(p & 0xFFFFFFFFu);
        out[s_star] = (float)labels[j];
    }
    if (s_star >= B_N) return;

    // exact sequential continuation (never expected to run on this data)
    for (int s = t; s < s_star; s += 1024) ref_idx[s] = s;
    __syncthreads();

    __shared__ unsigned long long redp[1024];
    __shared__ float redm[1024];
    for (int i = s_star + 1; i < B_N; i++) {
        int n = s_n;
        const float* xi = x + (size_t)i * D_DIM;
        float ni = norms[i];
        unsigned long long mp = 0xFFFFFFFFFFFFFFFFull;
        float mx = -INF_F;
        for (int slot = t; slot < n; slot += 1024) {
            int j = ref_idx[slot];
            const float* xj = x + (size_t)j * D_DIM;
            float dot = 0.f;
            for (int k = 0; k < D_DIM; k++) dot = fmaf(xi[k], xj[k], dot);
            float d = sqrtf(fmaxf(ni + norms[j] - 2.f * dot, 0.f));
            unsigned long long p =
                ((unsigned long long)__float_as_uint(d) << 32) | (unsigned)slot;
            if (p < mp) mp = p;
            mx = fmaxf(mx, d);
        }
        redp[t] = mp; redm[t] = mx;
        __syncthreads();
        for (int off = 512; off; off >>= 1) {
            if (t < off) {
                if (redp[t + off] < redp[t]) redp[t] = redp[t + off];
                redm[t] = fmaxf(redm[t], redm[t + off]);
            }
            __syncthreads();
        }
        if (t == 0) {
            unsigned long long p = redp[0];
            float min_act = __uint_as_float((unsigned)(p >> 32));
            int minslot   = (int)(unsigned)(p & 0xFFFFFFFFu);
            float max_act = redm[0];
            bool insert = (min_act > s_state[2]);
            int pred;
            if (insert) {
                ref_idx[n] = i;
                s_n = n + 1;
                pred = (min_act <= 0.0f) ? labels[ref_idx[minslot]] : labels[i];
            } else {
                pred = labels[ref_idx[minslot]];
            }
            float md = fminf(s_state[0], min_act);
            float Md = fmaxf(s_state[1], max_act);
            s_state[0] = md; s_state[1] = Md; s_state[2] = (md + Md) / 3.0f;
            out[i] = (float)pred;
        }
        __syncthreads();
    }
}

extern "C" void kernel_launch(void* const* d_in, const int* in_sizes, int n_in,
                              void* d_out, int out_size, void* d_ws, size_t ws_size,
                              hipStream_t stream) {
    const float* x      = (const float*)d_in[0];
    const int*   labels = (const int*)d_in[1];
    float*       out    = (float*)d_out;
    char* ws = (char*)d_ws;
    unsigned long long* minpack = (unsigned long long*)ws;
    unsigned int*       maxbits = (unsigned int*)(ws + 32768);
    float*              norms   = (float*)(ws + 49152);
    int*                ref_idx = (int*)(ws + 65600);
    unsigned short*     xbf     = (unsigned short*)(ws + XBF_OFF);

    k_prep<<<B_N, 256, 0, stream>>>(x, xbf, norms, minpack, maxbits);
    const int ntiles = B_N / 128;                        // 32
    const int nblocks = ntiles * (ntiles + 1) / 2;       // 528
    k_pass1_mfma<<<nblocks, 256, 0, stream>>>(xbf, norms, minpack, maxbits);
    k_tail<<<1, 1024, 0, stream>>>(minpack, maxbits, x, norms, labels, ref_idx, out);
}